// Round 4
// baseline (958.229 us; speedup 1.0000x reference)
//
#include <hip/hip_runtime.h>

#define BATCH 4096
#define NUM_CLASS 50257
#define NUM_SAMPLED 1024
#define BLOCK 128
#define PER_THREAD (NUM_SAMPLED / BLOCK)  // 8
#define NWAVE (BLOCK / 64)                // 2

// Kernel 1: one block per row. Gather true logit + 1024 sampled logits,
// stable logsumexp, write (logz - true_logit) per row into workspace.
// BLOCK=128 / 8 gathers per thread: 8 independent VMEM ops in flight per
// lane to cover ~900-cycle HBM gather latency (vs 4 before).
__global__ __launch_bounds__(BLOCK) void row_loss_kernel(
    const float* __restrict__ logits,
    const int* __restrict__ labels,
    const int* __restrict__ sampled_idx,
    float* __restrict__ row_out) {
  const int row = blockIdx.x;
  const int tid = threadIdx.x;

  const float* __restrict__ lrow = logits + (size_t)row * NUM_CLASS;
  const int* __restrict__ srow = sampled_idx + (size_t)row * NUM_SAMPLED;

  // Issue the (dependent, 2-deep) true-label chain first so it overlaps
  // the gather burst below instead of serializing after it.
  const int label = labels[row];

  // Two 16B coalesced loads for 8 indices per thread.
  const int4 iv0 = *reinterpret_cast<const int4*>(&srow[tid * PER_THREAD]);
  const int4 iv1 = *reinterpret_cast<const int4*>(&srow[tid * PER_THREAD + 4]);
  const int idx[PER_THREAD] = {iv0.x, iv0.y, iv0.z, iv0.w,
                               iv1.x, iv1.y, iv1.z, iv1.w};

  const float tl = lrow[label];

  // 8 independent gathers in flight per thread.
  float v[PER_THREAD];
#pragma unroll
  for (int k = 0; k < PER_THREAD; ++k) v[k] = lrow[idx[k]];

  // ---- block max ----
  float m = v[0];
#pragma unroll
  for (int k = 1; k < PER_THREAD; ++k) m = fmaxf(m, v[k]);
  m = fmaxf(m, tl);  // every lane includes it; max is idempotent
#pragma unroll
  for (int off = 32; off > 0; off >>= 1) m = fmaxf(m, __shfl_xor(m, off));

  __shared__ float smax[NWAVE];
  __shared__ float ssum[NWAVE];
  const int wave = tid >> 6;
  if ((tid & 63) == 0) smax[wave] = m;
  __syncthreads();
  const float bm = fmaxf(smax[0], smax[1]);

  // ---- block sum of exp ----
  float s = 0.f;
#pragma unroll
  for (int k = 0; k < PER_THREAD; ++k) s += expf(v[k] - bm);
  if (tid == 0) s += expf(tl - bm);  // true logit counted exactly once
#pragma unroll
  for (int off = 32; off > 0; off >>= 1) s += __shfl_xor(s, off);
  if ((tid & 63) == 0) ssum[wave] = s;
  __syncthreads();

  if (tid == 0) {
    row_out[row] = bm + logf(ssum[0] + ssum[1]) - tl;  // logz - true_logit
  }
}

// Kernel 2: deterministic mean over the 4096 per-row values.
__global__ __launch_bounds__(256) void reduce_mean_kernel(
    const float* __restrict__ row_vals, float* __restrict__ out) {
  const int tid = threadIdx.x;
  float s = 0.f;
  for (int i = tid; i < BATCH; i += 256) s += row_vals[i];
#pragma unroll
  for (int off = 32; off > 0; off >>= 1) s += __shfl_xor(s, off);
  __shared__ float ss[4];
  if ((tid & 63) == 0) ss[tid >> 6] = s;
  __syncthreads();
  if (tid == 0) out[0] = (ss[0] + ss[1] + ss[2] + ss[3]) * (1.0f / BATCH);
}

extern "C" void kernel_launch(void* const* d_in, const int* in_sizes, int n_in,
                              void* d_out, int out_size, void* d_ws, size_t ws_size,
                              hipStream_t stream) {
  const float* logits = (const float*)d_in[0];
  const int* labels = (const int*)d_in[1];
  const int* sampled_idx = (const int*)d_in[2];
  float* out = (float*)d_out;
  float* row_out = (float*)d_ws;  // 4096 floats = 16 KB

  row_loss_kernel<<<BATCH, BLOCK, 0, stream>>>(logits, labels, sampled_idx, row_out);
  reduce_mean_kernel<<<1, 256, 0, stream>>>(row_out, out);
}